// Round 1
// 2705.052 us; speedup vs baseline: 1.0327x; 1.0327x over previous
//
#include <hip/hip_runtime.h>
#include <math.h>

#define N_ROWS 10816   // 64 * 169 rows per timestep
#define T_SEQ 55
#define NPIX 169

__device__ __forceinline__ unsigned short f2bf(float f){
    unsigned u = __float_as_uint(f);
    unsigned r = u + 0x7FFFu + ((u>>16)&1u);
    return (unsigned short)(r>>16);
}
__device__ __forceinline__ float bf2f(unsigned short h){
    return __uint_as_float(((unsigned)h)<<16);
}

// native-exp activations (v_exp_f32 based). NaN-safe at extremes:
// sigm: exp(-x)->inf => 1/inf = 0 (IEEE div). tanh via |x| + copysign.
__device__ __forceinline__ float fast_sig(float x){
    return 1.0f/(1.0f + __expf(-x));
}
__device__ __forceinline__ float fast_tanh(float x){
    float ax = fabsf(x);
    float e  = __expf(-2.0f*ax);           // (0,1]
    float r  = (1.0f - e)/(1.0f + e);
    return copysignf(r, x);
}

typedef __attribute__((ext_vector_type(8))) short bfrag;
typedef __attribute__((ext_vector_type(4))) float facc;

// ---------------------------------------------------------------------------
// Kernel 1: fused input transpose + 4x (1x1 conv + ReLU) chain. (unchanged)
// ---------------------------------------------------------------------------
__global__ __launch_bounds__(256) void conv1x1_chain(
    const float* __restrict__ x,
    const float* __restrict__ w0, const float* __restrict__ b0,
    const float* __restrict__ w1, const float* __restrict__ b1,
    const float* __restrict__ w2, const float* __restrict__ b2,
    const float* __restrict__ w3, const float* __restrict__ b3,
    float* __restrict__ out)
{
    int n = blockIdx.x*256 + threadIdx.x;
    int l = blockIdx.y;
    if (n >= N_ROWS) return;
    const float* xp = x + ((size_t)n*T_SEQ + l)*24;
    float in24[24];
    #pragma unroll
    for (int i=0;i<6;i++){
        float4 v = *(const float4*)(xp + 4*i);
        in24[4*i]=v.x; in24[4*i+1]=v.y; in24[4*i+2]=v.z; in24[4*i+3]=v.w;
    }
    float a[30], c[30];
    #pragma unroll
    for (int co=0;co<30;co++) a[co]=b0[co];
    #pragma unroll
    for (int ci=0;ci<24;ci++){
        float v = in24[ci];
        #pragma unroll
        for (int co=0;co<30;co++) a[co] = fmaf(v, w0[ci*30+co], a[co]);
    }
    #pragma unroll
    for (int co=0;co<30;co++) a[co] = fmaxf(a[co],0.f);

#define LAYER30(wp, bp) \
    { _Pragma("unroll") for (int co=0;co<30;co++) c[co]=(bp)[co]; \
      _Pragma("unroll") for (int ci=0;ci<30;ci++){ float v=a[ci]; \
        _Pragma("unroll") for (int co=0;co<30;co++) c[co]=fmaf(v,(wp)[ci*30+co],c[co]); } \
      _Pragma("unroll") for (int co=0;co<30;co++) a[co]=fmaxf(c[co],0.f); }

    LAYER30(w1,b1);
    LAYER30(w2,b2);
    LAYER30(w3,b3);
#undef LAYER30

    float* op = out + (size_t)l*30*N_ROWS + n;
    #pragma unroll
    for (int co=0;co<30;co++) op[(size_t)co*N_ROWS] = a[co];
}

// ---------------------------------------------------------------------------
// Kernel 2: 5x5 SAME conv + ReLU, channel-major, IN-PLACE. (unchanged)
// ---------------------------------------------------------------------------
__global__ __launch_bounds__(192) void conv5x5(
    float* __restrict__ buf, const float* __restrict__ w,
    const float* __restrict__ bias)
{
    __shared__ float img[15*289];
    int bi = blockIdx.x;
    int l = bi >> 6;
    int b = bi & 63;
    float* ip = buf + (size_t)l*30*N_ROWS + (size_t)b*NPIX;
    int tid = threadIdx.x;

    int p = tid;
    bool act = p < 169;
    int pc = act ? p : 0;
    int y = pc/13, x0 = pc - y*13;

    float acc[30];
    #pragma unroll
    for (int co=0;co<30;co++) acc[co]=bias[co];

    for (int i = tid; i < 15*289; i += 192) img[i] = 0.f;

    for (int half = 0; half < 2; half++){
        __syncthreads();
        for (int i = tid; i < 15*169; i += 192){
            int ci = i/169, pp = i - ci*169;
            int yy = pp/13, xx = pp - yy*13;
            img[ci*289 + (yy+2)*17 + (xx+2)] =
                ip[(size_t)(half*15 + ci)*N_ROWS + pp];
        }
        __syncthreads();
        for (int dy=0; dy<5; dy++){
          for (int dx=0; dx<5; dx++){
            const float* wp = w + (size_t)((dy*5+dx)*30 + half*15)*30;
            const float* im = img + (y+dy)*17 + (x0+dx);
            #pragma unroll
            for (int ci=0; ci<15; ci++){
              float v = im[ci*289];
              #pragma unroll
              for (int co=0;co<30;co++) acc[co] = fmaf(v, wp[ci*30+co], acc[co]);
            }
          }
        }
    }
    if (act){
      #pragma unroll
      for (int co=0;co<30;co++) ip[(size_t)co*N_ROWS + p] = fmaxf(acc[co],0.f);
    }
}

// ---------------------------------------------------------------------------
// Kernel 3: MFMA weight repack, bf16 hi/lo split. (unchanged)
// ---------------------------------------------------------------------------
__global__ __launch_bounds__(256) void repack_mfma(
    const float* __restrict__ l1w, const float* __restrict__ l1b,
    const float* __restrict__ l2w, const float* __restrict__ l2b,
    unsigned short* __restrict__ bw1h, unsigned short* __restrict__ bw1l,
    unsigned short* __restrict__ bw2h, unsigned short* __restrict__ bw2l,
    float* __restrict__ pbias1, float* __restrict__ pbias2)
{
    const int S1 = 5*32*512;   // 81920
    const int S2 = 7*32*512;   // 114688
    int i = blockIdx.x*256 + threadIdx.x;
    if (i < S1){
        int fr = i >> 9, r = i & 511;
        int kt = fr >> 5, ct = fr & 31;
        int lane = r >> 3, j = r & 7;
        int k = kt*32 + ((lane>>4)<<3) + j;
        int n = lane & 15;
        int cell = ((ct>>2)<<4) + n, g = ct & 3;
        float w = (k<130 && cell<100) ? l1w[(size_t)k*400 + g*100 + cell] : 0.f;
        unsigned short h = f2bf(w);
        bw1h[i] = h; bw1l[i] = f2bf(w - bf2f(h));
    } else if (i < S1 + S2){
        int ii = i - S1;
        int fr = ii >> 9, r = ii & 511;
        int kt = fr >> 5, ct = fr & 31;
        int lane = r >> 3, j = r & 7;
        int k = kt*32 + ((lane>>4)<<3) + j;
        int n = lane & 15;
        int cell = ((ct>>2)<<4) + n, g = ct & 3;
        float w = (k<200 && cell<100) ? l2w[(size_t)k*400 + g*100 + cell] : 0.f;
        unsigned short h = f2bf(w);
        bw2h[ii] = h; bw2l[ii] = f2bf(w - bf2f(h));
    } else if (i < S1+S2+512){
        int col = i - S1 - S2;
        int ct = col >> 4, n = col & 15;
        int cell = ((ct>>2)<<4) + n, g = ct & 3;
        pbias1[col] = (cell<100) ? l1b[g*100+cell] : 0.f;
    } else if (i < S1+S2+1024){
        int col = i - S1 - S2 - 512;
        int ct = col >> 4, n = col & 15;
        int cell = ((ct>>2)<<4) + n, g = ct & 3;
        pbias2[col] = (cell<100) ? l2b[g*100+cell] : 0.f;
    }
}

// ---------------------------------------------------------------------------
// Kernel 4: PERSISTENT 2-layer LSTM + projection, v4.
// Changes vs v3 (theory: VALU-stall-bound, not MFMA/HBM):
//  - A staged as PRE-SPLIT bf16 hi/lo in LDS, layout [kt][16 rows][32 k]
//    ushort: each lane ds_read_b128's a distinct 16B chunk (conflict-free),
//    and the fp32->bf16 split happens ONCE (epilogue/stage) instead of
//    per-kt per-wave (was ~1150 VALU instr/wave/step, 4x redundant).
//  - 3-term split MFMA (drop al*bl ~ 2^-16|ab|, same order as the split
//    residual): 24 MFMA/kt instead of 32.
//  - MFMA passes interleaved (hh x8, lh x8, hl x8): dependent accumulator
//    reuse gap = 8 MFMAs (~40 cyc) instead of back-to-back.
//  - native-exp sigmoid/tanh (v_exp_f32), NaN-safe.
//  - projection in-register: shfl_xor reduce over the 16-lane group, no
//    100-cell LDS loop.  Barriers/step: 6 -> 4.
//  - x(t+1) prefetched into VGPR at loop top, staged during EPI1 phase.
// ---------------------------------------------------------------------------
#define NKT1 5
#define NKT2 7
__global__ __launch_bounds__(256, 3) void lstm_mfma3(
    const float* __restrict__ xall,   // [55][30][N]
    const unsigned short* __restrict__ bw1h, const unsigned short* __restrict__ bw1l,
    const unsigned short* __restrict__ bw2h, const unsigned short* __restrict__ bw2l,
    const float* __restrict__ pbias1, const float* __restrict__ pbias2,
    const float* __restrict__ we, const float* __restrict__ be,
    float* __restrict__ out)          // [N][55]
{
    // A matrices as bf16 hi/lo, layout [kt][row(16)][kcol(32)] ushort
    __shared__ __align__(16) unsigned short A1h[NKT1*512];
    __shared__ __align__(16) unsigned short A1l[NKT1*512];
    __shared__ __align__(16) unsigned short A2h[NKT2*512];
    __shared__ __align__(16) unsigned short A2l[NKT2*512];
    __shared__ float pbuf[64];

    const int tid  = threadIdx.x;
    const int wave = tid >> 6, lane = tid & 63;
    const int m16  = lane & 15, quad = lane >> 4;
    const int n0   = blockIdx.x * 16;
    const int cl0  = wave*2;              // my 2 cell-tiles
    const int cell0 = cl0*16 + m16;
    const int cell1 = cell0 + 16;

    for (int i=tid; i<NKT1*512; i+=256){ A1h[i]=0; A1l[i]=0; }
    for (int i=tid; i<NKT2*512; i+=256){ A2h[i]=0; A2l[i]=0; }

    float cs1a[4]={0,0,0,0}, cs1b[4]={0,0,0,0};
    float cs2a[4]={0,0,0,0}, cs2b[4]={0,0,0,0};
    float b1a[4], b1b[4], b2a[4], b2b[4];
    #pragma unroll
    for (int g=0; g<4; g++){
        b1a[g] = pbias1[(cl0*4+g)*16 + m16];
        b1b[g] = pbias1[((cl0+1)*4+g)*16 + m16];
        b2a[g] = pbias2[(cl0*4+g)*16 + m16];
        b2b[g] = pbias2[((cl0+1)*4+g)*16 + m16];
    }
    const float weA = (cell0 < 100) ? we[cell0] : 0.f;
    const float weB = (cell1 < 100) ? we[cell1] : 0.f;
    const float be0 = be[0];

    // weight fragment bases (per kt: advance 32*64*8 = 16384 ushorts)
    const unsigned short* w1h0 = bw1h + ((size_t)(cl0*4)*64 + lane)*8;
    const unsigned short* w1l0 = bw1l + ((size_t)(cl0*4)*64 + lane)*8;
    const unsigned short* w2h0 = bw2h + ((size_t)(cl0*4)*64 + lane)*8;
    const unsigned short* w2l0 = bw2l + ((size_t)(cl0*4)*64 + lane)*8;

    const int sk = tid >> 2, sq = tid & 3;   // staging role (tid<120)

    __syncthreads();   // zero-init visible

    // stage x(0): column sk, rows sq*4..sq*4+3 (all in kt=0, k<30)
    if (tid < 120){
        float4 v = *(const float4*)(xall + (size_t)sk*N_ROWS + n0 + sq*4);
        float vv[4] = {v.x, v.y, v.z, v.w};
        #pragma unroll
        for (int j=0;j<4;j++){
            unsigned short hh = f2bf(vv[j]);
            A1h[(sq*4+j)*32 + sk] = hh;
            A1l[(sq*4+j)*32 + sk] = f2bf(vv[j] - bf2f(hh));
        }
    }
    __syncthreads();

    facc acA[4], acB[4];

// 3-term split GEMM, pass-interleaved. kt loop NOT unrolled (spill control).
#define GEMM(WH0, WL0, NKT, AH, AL, BIA, BIB) \
    { _Pragma("unroll") \
      for (int g=0; g<4; g++){ \
          acA[g]=(facc){(BIA)[g],(BIA)[g],(BIA)[g],(BIA)[g]}; \
          acB[g]=(facc){(BIB)[g],(BIB)[g],(BIB)[g],(BIB)[g]}; } \
      _Pragma("unroll 1") \
      for (int kt=0; kt<(NKT); kt++){ \
        bfrag ah = *(const bfrag*)((AH) + (kt<<9) + (m16<<5) + (quad<<3)); \
        bfrag al = *(const bfrag*)((AL) + (kt<<9) + (m16<<5) + (quad<<3)); \
        const unsigned short* whp = (WH0) + (size_t)kt*16384; \
        const unsigned short* wlp = (WL0) + (size_t)kt*16384; \
        bfrag bh[8], bl[8]; \
        _Pragma("unroll") \
        for (int g=0; g<8; g++){ \
            bh[g] = *(const bfrag*)(whp + (size_t)g*512); \
            bl[g] = *(const bfrag*)(wlp + (size_t)g*512); } \
        _Pragma("unroll") \
        for (int g=0; g<4; g++){ \
            acA[g]=__builtin_amdgcn_mfma_f32_16x16x32_bf16(ah,bh[g],  acA[g],0,0,0); \
            acB[g]=__builtin_amdgcn_mfma_f32_16x16x32_bf16(ah,bh[4+g],acB[g],0,0,0); } \
        _Pragma("unroll") \
        for (int g=0; g<4; g++){ \
            acA[g]=__builtin_amdgcn_mfma_f32_16x16x32_bf16(al,bh[g],  acA[g],0,0,0); \
            acB[g]=__builtin_amdgcn_mfma_f32_16x16x32_bf16(al,bh[4+g],acB[g],0,0,0); } \
        _Pragma("unroll") \
        for (int g=0; g<4; g++){ \
            acA[g]=__builtin_amdgcn_mfma_f32_16x16x32_bf16(ah,bl[g],  acA[g],0,0,0); \
            acB[g]=__builtin_amdgcn_mfma_f32_16x16x32_bf16(ah,bl[4+g],acB[g],0,0,0); } \
      } }

#define LSTM_CELL(AC, CS, H4) \
    { _Pragma("unroll") \
      for (int i2=0;i2<4;i2++){ \
        float gi = fast_sig((AC)[0][i2]); \
        float gj = fast_tanh((AC)[1][i2]); \
        float gf = fast_sig((AC)[2][i2] + 1.0f); \
        float go = fast_sig((AC)[3][i2]); \
        float cn = gf*(CS)[i2] + gi*gj; \
        (CS)[i2] = cn; \
        (H4)[i2] = go*fast_tanh(cn); } }

    for (int t=0; t<T_SEQ; t++){
        // prefetch x(t+1); latency hidden under GEMM1
        float4 xn;
        if (t+1 < T_SEQ && tid < 120)
            xn = *(const float4*)(xall + ((size_t)(t+1)*30+sk)*N_ROWS + n0 + sq*4);

        GEMM(w1h0, w1l0, NKT1, A1h, A1l, b1a, b1b);        // layer 1
        __syncthreads();                                   // B1

        // EPI1: h1 -> A1 (k=30+cell) and A2 (k=cell), split once
        {
            float hA[4], hB[4];
            LSTM_CELL(acA, cs1a, hA);
            LSTM_CELL(acB, cs1b, hB);
            #pragma unroll
            for (int i2=0;i2<4;i2++){
                int row = quad*4 + i2;
                if (cell0 < 100){
                    unsigned short hh = f2bf(hA[i2]);
                    unsigned short hl = f2bf(hA[i2] - bf2f(hh));
                    int k1 = 30 + cell0;
                    int a1 = ((k1>>5)<<9) + (row<<5) + (k1&31);
                    int a2 = ((cell0>>5)<<9) + (row<<5) + (cell0&31);
                    A1h[a1]=hh; A1l[a1]=hl;
                    A2h[a2]=hh; A2l[a2]=hl;
                }
                if (cell1 < 100){
                    unsigned short hh = f2bf(hB[i2]);
                    unsigned short hl = f2bf(hB[i2] - bf2f(hh));
                    int k1 = 30 + cell1;
                    int a1 = ((k1>>5)<<9) + (row<<5) + (k1&31);
                    int a2 = ((cell1>>5)<<9) + (row<<5) + (cell1&31);
                    A1h[a1]=hh; A1l[a1]=hl;
                    A2h[a2]=hh; A2l[a2]=hl;
                }
            }
            // stage x(t+1) into A1 (GEMM1(t) already read it; next read after B2)
            if (t+1 < T_SEQ && tid < 120){
                float vv[4] = {xn.x, xn.y, xn.z, xn.w};
                #pragma unroll
                for (int j=0;j<4;j++){
                    unsigned short hh = f2bf(vv[j]);
                    A1h[(sq*4+j)*32 + sk] = hh;
                    A1l[(sq*4+j)*32 + sk] = f2bf(vv[j] - bf2f(hh));
                }
            }
        }
        __syncthreads();                                   // B2

        GEMM(w2h0, w2l0, NKT2, A2h, A2l, b2a, b2b);        // layer 2
        __syncthreads();                                   // B3

        // EPI2: h2 -> A2 (k=100+cell) + in-register projection partial
        {
            float hA[4], hB[4], pp[4];
            LSTM_CELL(acA, cs2a, hA);
            LSTM_CELL(acB, cs2b, hB);
            #pragma unroll
            for (int i2=0;i2<4;i2++){
                int row = quad*4 + i2;
                if (cell0 < 100){
                    unsigned short hh = f2bf(hA[i2]);
                    unsigned short hl = f2bf(hA[i2] - bf2f(hh));
                    int k1 = 100 + cell0;
                    int a1 = ((k1>>5)<<9) + (row<<5) + (k1&31);
                    A2h[a1]=hh; A2l[a1]=hl;
                }
                if (cell1 < 100){
                    unsigned short hh = f2bf(hB[i2]);
                    unsigned short hl = f2bf(hB[i2] - bf2f(hh));
                    int k1 = 100 + cell1;
                    int a1 = ((k1>>5)<<9) + (row<<5) + (k1&31);
                    A2h[a1]=hh; A2l[a1]=hl;
                }
                pp[i2] = hA[i2]*weA + hB[i2]*weB;   // we==0 pads cells>=100
            }
            // reduce over the 16 lanes (m16) of this quad group
            #pragma unroll
            for (int i2=0;i2<4;i2++){
                float p = pp[i2];
                p += __shfl_xor(p, 1);
                p += __shfl_xor(p, 2);
                p += __shfl_xor(p, 4);
                p += __shfl_xor(p, 8);
                pp[i2] = p;
            }
            if (m16 == 0){
                #pragma unroll
                for (int i2=0;i2<4;i2++)
                    pbuf[wave*16 + quad*4 + i2] = pp[i2];
            }
        }
        __syncthreads();                                   // B4

        if (tid < 16){
            float s = be0 + pbuf[tid] + pbuf[16+tid] + pbuf[32+tid] + pbuf[48+tid];
            out[(size_t)(n0+tid)*T_SEQ + t] = s;
        }
    }
#undef GEMM
#undef LSTM_CELL
}

// ---------------------------------------------------------------------------
extern "C" void kernel_launch(void* const* d_in, const int* in_sizes, int n_in,
                              void* d_out, int out_size, void* d_ws, size_t ws_size,
                              hipStream_t stream)
{
    const float* x    = (const float*)d_in[0];
    const float* w10  = (const float*)d_in[1];  const float* b10 = (const float*)d_in[2];
    const float* w11  = (const float*)d_in[3];  const float* b11 = (const float*)d_in[4];
    const float* w12  = (const float*)d_in[5];  const float* b12 = (const float*)d_in[6];
    const float* w13  = (const float*)d_in[7];  const float* b13 = (const float*)d_in[8];
    const float* w20  = (const float*)d_in[9];  const float* b20 = (const float*)d_in[10];
    const float* w21  = (const float*)d_in[11]; const float* b21 = (const float*)d_in[12];
    const float* w22  = (const float*)d_in[13]; const float* b22 = (const float*)d_in[14];
    const float* w23  = (const float*)d_in[15]; const float* b23 = (const float*)d_in[16];
    const float* l1w  = (const float*)d_in[17]; const float* l1b = (const float*)d_in[18];
    const float* l2w  = (const float*)d_in[19]; const float* l2b = (const float*)d_in[20];
    const float* we   = (const float*)d_in[21]; const float* be  = (const float*)d_in[22];
    float* out = (float*)d_out;

    // workspace: conv slab 71.4 MB + packed bf16 weights ~0.8 MB + biases
    const size_t NF = (size_t)30*N_ROWS;
    float* buf0 = (float*)d_ws;                       // [55][30][N] floats
    unsigned short* bw1h = (unsigned short*)(buf0 + (size_t)T_SEQ*NF);
    unsigned short* bw1l = bw1h + 5*32*512;           // 81920 each
    unsigned short* bw2h = bw1l + 5*32*512;
    unsigned short* bw2l = bw2h + 7*32*512;           // 114688 each
    float* pbias1 = (float*)(bw2l + 7*32*512);
    float* pbias2 = pbias1 + 512;

    const int REPACK_N = 5*32*512 + 7*32*512 + 1024;
    repack_mfma<<<(REPACK_N+255)/256, 256, 0, stream>>>(
        l1w, l1b, l2w, l2b, bw1h, bw1l, bw2h, bw2l, pbias1, pbias2);

    dim3 g1((N_ROWS+255)/256, T_SEQ);
    conv1x1_chain<<<g1, 256, 0, stream>>>(x, w10,b10, w11,b11, w12,b12, w13,b13, buf0);
    conv5x5<<<T_SEQ*64, 192, 0, stream>>>(buf0, w20, b20);
    conv5x5<<<T_SEQ*64, 192, 0, stream>>>(buf0, w21, b21);
    conv5x5<<<T_SEQ*64, 192, 0, stream>>>(buf0, w22, b22);
    conv5x5<<<T_SEQ*64, 192, 0, stream>>>(buf0, w23, b23);

    lstm_mfma3<<<N_ROWS/16, 256, 0, stream>>>(buf0, bw1h, bw1l, bw2h, bw2l,
                                              pbias1, pbias2, we, be, out);
}